// Round 1
// baseline (649.383 us; speedup 1.0000x reference)
//
#include <hip/hip_runtime.h>

// Problem constants
#define B_    2
#define COND_ 4
#define C_    128
#define S_    32768      // H*W*D = 32*32*32
#define NH_   8
#define TS_   64         // voxels per block tile
// thread mapping: tid = g*32 + st ; g = head/channel-group (16 ch), st = voxel-pair idx
// each thread owns channels [g*16, g*16+16) x 2 voxels (s0 + st*2 + {0,1})

#define GEMM_Q(SRC, ACC)                                                      \
  _Pragma("unroll 4")                                                         \
  for (int c4 = 0; c4 < 32; ++c4) {                                           \
    const float4 w0_ = *(const float4*)&wbuf[(g << 2) + 0][c4 << 2];          \
    const float4 w1_ = *(const float4*)&wbuf[(g << 2) + 1][c4 << 2];          \
    const float4 w2_ = *(const float4*)&wbuf[(g << 2) + 2][c4 << 2];          \
    const float4 w3_ = *(const float4*)&wbuf[(g << 2) + 3][c4 << 2];          \
    const float2 x0_ = *(const float2*)&SRC[(c4 << 2) + 0][st << 1];          \
    const float2 x1_ = *(const float2*)&SRC[(c4 << 2) + 1][st << 1];          \
    const float2 x2_ = *(const float2*)&SRC[(c4 << 2) + 2][st << 1];          \
    const float2 x3_ = *(const float2*)&SRC[(c4 << 2) + 3][st << 1];          \
    ACC[0][0] += w0_.x * x0_.x + w0_.y * x1_.x + w0_.z * x2_.x + w0_.w * x3_.x; \
    ACC[0][1] += w0_.x * x0_.y + w0_.y * x1_.y + w0_.z * x2_.y + w0_.w * x3_.y; \
    ACC[1][0] += w1_.x * x0_.x + w1_.y * x1_.x + w1_.z * x2_.x + w1_.w * x3_.x; \
    ACC[1][1] += w1_.x * x0_.y + w1_.y * x1_.y + w1_.z * x2_.y + w1_.w * x3_.y; \
    ACC[2][0] += w2_.x * x0_.x + w2_.y * x1_.x + w2_.z * x2_.x + w2_.w * x3_.x; \
    ACC[2][1] += w2_.x * x0_.y + w2_.y * x1_.y + w2_.z * x2_.y + w2_.w * x3_.y; \
    ACC[3][0] += w3_.x * x0_.x + w3_.y * x1_.x + w3_.z * x2_.x + w3_.w * x3_.x; \
    ACC[3][1] += w3_.x * x0_.y + w3_.y * x1_.y + w3_.z * x2_.y + w3_.w * x3_.y; \
  }

__global__ __launch_bounds__(256, 2) void attn_kernel(
    const float* __restrict__ skip,   // [B][COND][C][S]
    const float* __restrict__ dec,    // [B][C][S]
    const float* __restrict__ wq, const float* __restrict__ wk,
    const float* __restrict__ wv,
    const float* __restrict__ bq, const float* __restrict__ bk,
    const float* __restrict__ bv,
    const float* __restrict__ wo, const float* __restrict__ bo,
    float* __restrict__ attn_out,     // [B][C][S]  (workspace)
    float* __restrict__ stats)        // [B][8][2]  (sum, sumsq)
{
  __shared__ float sx[C_][TS_];    // 32 KB decoder tile (kept for residual)
  __shared__ float sy[C_][TS_];    // 32 KB skip tile / o_pre staging
  __shared__ float wbuf[32][128];  // 16 KB weight quarter (head-gathered rows)

  const int tid = threadIdx.x;
  const int g  = tid >> 5;   // 0..7
  const int st = tid & 31;   // 0..31
  const int b  = blockIdx.y;
  const int s0 = blockIdx.x * TS_;

  // ---- load decoder tile: sx[c][ss] = dec[b][c][s0+ss] ----
  {
    const float* base = dec + (size_t)b * C_ * S_ + s0;
    #pragma unroll
    for (int i = 0; i < 8; ++i) {
      int l = i * 256 + tid;              // 0..2047 float4s
      int c = l >> 4, ss4 = l & 15;
      *(float4*)&sx[c][ss4 * 4] = *(const float4*)(base + (size_t)c * S_ + ss4 * 4);
    }
  }

  // weight-quarter loader: rows r = g2*16 + qq*4 + j  ->  wbuf[g2*4+j][*]
  #define LOADW(W, QQ)                                                        \
    _Pragma("unroll")                                                         \
    for (int i = 0; i < 4; ++i) {                                             \
      int l = i * 256 + tid;            /* 0..1023 float4s */                 \
      int lr = l >> 5, cq = l & 31;                                           \
      int r = (lr >> 2) * 16 + (QQ) * 4 + (lr & 3);                           \
      *(float4*)&wbuf[lr][cq * 4] = *(const float4*)((W) + r * 128 + cq * 4); \
    }

  float qv[16][2];
  float sc[COND_][2];
  #pragma unroll
  for (int c = 0; c < COND_; ++c) { sc[c][0] = 0.f; sc[c][1] = 0.f; }

  // ---- P1: q projection ----
  for (int qq = 0; qq < 4; ++qq) {
    __syncthreads();
    LOADW(wq, qq);
    __syncthreads();
    float acc[4][2];
    #pragma unroll
    for (int j = 0; j < 4; ++j) {
      float bb = bq[g * 16 + qq * 4 + j];
      acc[j][0] = bb; acc[j][1] = bb;
    }
    GEMM_Q(sx, acc);
    #pragma unroll
    for (int j = 0; j < 4; ++j) {
      qv[qq * 4 + j][0] = acc[j][0];
      qv[qq * 4 + j][1] = acc[j][1];
    }
  }

  // ---- P2: scores (k projection, dot with q) ----
  for (int cond = 0; cond < COND_; ++cond) {
    __syncthreads();
    {
      const float* ybase = skip + ((size_t)b * COND_ + cond) * C_ * S_ + s0;
      #pragma unroll
      for (int i = 0; i < 8; ++i) {
        int l = i * 256 + tid;
        int c = l >> 4, ss4 = l & 15;
        *(float4*)&sy[c][ss4 * 4] = *(const float4*)(ybase + (size_t)c * S_ + ss4 * 4);
      }
    }
    for (int qq = 0; qq < 4; ++qq) {
      __syncthreads();
      LOADW(wk, qq);
      __syncthreads();
      float acc[4][2];
      #pragma unroll
      for (int j = 0; j < 4; ++j) {
        float bb = bk[g * 16 + qq * 4 + j];
        acc[j][0] = bb; acc[j][1] = bb;
      }
      GEMM_Q(sy, acc);
      #pragma unroll
      for (int j = 0; j < 4; ++j) {
        sc[cond][0] += qv[qq * 4 + j][0] * acc[j][0];
        sc[cond][1] += qv[qq * 4 + j][1] * acc[j][1];
      }
    }
  }

  // ---- softmax over cond (scale 1/sqrt(16) = 0.25), fully thread-local ----
  float attnw[COND_][2];
  #pragma unroll
  for (int ss = 0; ss < 2; ++ss) {
    float m = -1e30f;
    #pragma unroll
    for (int c = 0; c < COND_; ++c) m = fmaxf(m, sc[c][ss] * 0.25f);
    float sum = 0.f, e[COND_];
    #pragma unroll
    for (int c = 0; c < COND_; ++c) { e[c] = expf(sc[c][ss] * 0.25f - m); sum += e[c]; }
    float inv = 1.f / sum;
    #pragma unroll
    for (int c = 0; c < COND_; ++c) attnw[c][ss] = e[c] * inv;
  }

  // ---- P3: v projection + attention-weighted accumulation ----
  float ov[16][2];
  #pragma unroll
  for (int i = 0; i < 16; ++i) {       // sum_k attn = 1 -> bias passes through
    float bb = bv[g * 16 + i];
    ov[i][0] = bb; ov[i][1] = bb;
  }
  for (int cond = 0; cond < COND_; ++cond) {
    __syncthreads();
    {
      const float* ybase = skip + ((size_t)b * COND_ + cond) * C_ * S_ + s0;
      #pragma unroll
      for (int i = 0; i < 8; ++i) {
        int l = i * 256 + tid;
        int c = l >> 4, ss4 = l & 15;
        *(float4*)&sy[c][ss4 * 4] = *(const float4*)(ybase + (size_t)c * S_ + ss4 * 4);
      }
    }
    for (int qq = 0; qq < 4; ++qq) {
      __syncthreads();
      LOADW(wv, qq);
      __syncthreads();
      float acc[4][2] = {{0.f,0.f},{0.f,0.f},{0.f,0.f},{0.f,0.f}};
      GEMM_Q(sy, acc);
      #pragma unroll
      for (int j = 0; j < 4; ++j) {
        ov[qq * 4 + j][0] += attnw[cond][0] * acc[j][0];
        ov[qq * 4 + j][1] += attnw[cond][1] * acc[j][1];
      }
    }
  }

  // ---- P4: stage o_pre into LDS (reuse sy), out projection + residual + GN stats ----
  __syncthreads();
  #pragma unroll
  for (int i = 0; i < 16; ++i)
    *(float2*)&sy[g * 16 + i][st << 1] = make_float2(ov[i][0], ov[i][1]);

  float gsum = 0.f, gsq = 0.f;
  float* obase = attn_out + (size_t)b * C_ * S_ + s0;
  for (int qq = 0; qq < 4; ++qq) {
    __syncthreads();
    LOADW(wo, qq);
    __syncthreads();
    float acc[4][2];
    #pragma unroll
    for (int j = 0; j < 4; ++j) {
      float bb = bo[g * 16 + qq * 4 + j];
      acc[j][0] = bb; acc[j][1] = bb;
    }
    GEMM_Q(sy, acc);
    #pragma unroll
    for (int j = 0; j < 4; ++j) {
      int r = g * 16 + qq * 4 + j;
      float o0 = acc[j][0] + sx[r][(st << 1) + 0];
      float o1 = acc[j][1] + sx[r][(st << 1) + 1];
      *(float2*)(obase + (size_t)r * S_ + (st << 1)) = make_float2(o0, o1);
      gsum += o0 + o1;
      gsq  += o0 * o0 + o1 * o1;
    }
  }

  // half-wave (32 lanes, same g) reduction, then one atomic per (block, g)
  #pragma unroll
  for (int off = 16; off >= 1; off >>= 1) {
    gsum += __shfl_xor(gsum, off, 32);
    gsq  += __shfl_xor(gsq,  off, 32);
  }
  if (st == 0) {
    atomicAdd(&stats[(b * 8 + g) * 2 + 0], gsum);
    atomicAdd(&stats[(b * 8 + g) * 2 + 1], gsq);
  }
}

__global__ void gn_kernel(const float* __restrict__ src, const float* __restrict__ stats,
                          const float* __restrict__ gamma, const float* __restrict__ beta,
                          float* __restrict__ out)
{
  const int n4 = B_ * C_ * S_ / 4;
  const float inv_n = 1.0f / (16.0f * S_);
  int i = blockIdx.x * blockDim.x + threadIdx.x;
  for (; i < n4; i += gridDim.x * blockDim.x) {
    int bc = i >> 13;                 // S_/4 = 8192 float4 per (b,c)
    int b = bc >> 7, c = bc & 127;
    int gi = (b * 8 + (c >> 4)) * 2;
    float mu  = stats[gi] * inv_n;
    float var = stats[gi + 1] * inv_n - mu * mu;
    float rs  = rsqrtf(var + 1e-5f);
    float ga  = gamma[c] * rs;
    float be  = beta[c] - mu * ga;
    float4 v = ((const float4*)src)[i];
    float4 o;
    o.x = v.x * ga + be; o.y = v.y * ga + be;
    o.z = v.z * ga + be; o.w = v.w * ga + be;
    ((float4*)out)[i] = o;
  }
}

extern "C" void kernel_launch(void* const* d_in, const int* in_sizes, int n_in,
                              void* d_out, int out_size, void* d_ws, size_t ws_size,
                              hipStream_t stream) {
  const float* skip  = (const float*)d_in[0];
  const float* dec   = (const float*)d_in[1];
  const float* wq    = (const float*)d_in[2];
  const float* wk    = (const float*)d_in[3];
  const float* wv    = (const float*)d_in[4];
  const float* bq    = (const float*)d_in[5];
  const float* bk    = (const float*)d_in[6];
  const float* bv    = (const float*)d_in[7];
  const float* wo    = (const float*)d_in[8];
  const float* bo    = (const float*)d_in[9];
  const float* gamma = (const float*)d_in[10];
  const float* beta  = (const float*)d_in[11];

  float* out     = (float*)d_out;
  float* ws_attn = (float*)d_ws;                          // B*C*S floats = 32 MB
  float* stats   = ws_attn + (size_t)B_ * C_ * S_;        // 32 floats

  hipMemsetAsync(stats, 0, 32 * sizeof(float), stream);

  dim3 grid(S_ / TS_, B_);   // 512 x 2
  attn_kernel<<<grid, 256, 0, stream>>>(skip, dec, wq, wk, wv, bq, bk, bv, wo, bo,
                                        ws_attn, stats);
  gn_kernel<<<2048, 256, 0, stream>>>(ws_attn, stats, gamma, beta, out);
}